// Round 11
// baseline (3238.921 us; speedup 1.0000x reference)
//
#include <hip/hip_runtime.h>
#include <stdint.h>

#define BATCH   4
#define NPTS    16384
#define NPOINT  1024
#define KNN     20
#define KSEL    21   // K+1, includes self

// ---------------------------------------------------------------------------
// FPS: one block per batch, 512 threads, 32 points/thread, coords + min_d in
// AGPRs. r5-r10 forensic: per-iter cost ~5600 cyc invariant across scratch /
// LDS / pinned-VGPR data paths; VALU issue ~27 instr/pt (vs ~10 needed) =
// allocator spill/remat bloat; it caps arch-VGPRs at 48-92 in every config.
// Fix: park px/py/pz/md in the OTHER half of the unified 512-reg file via
// explicit v_accvgpr_read/write_b32 ("a" constraint). Asm defs/uses force
// AGPR-class live ranges (never spilled/remat'd); reads carry a dummy
// loop-variant operand so they schedule freely in-iteration but can't hoist.
// accvgpr moves are bit-exact copies; distance expression text is unchanged
// from the validated r5 binary -> identical selections.
// ---------------------------------------------------------------------------
#define FPS_THREADS 512
#define PPT (NPTS / FPS_THREADS)  // 32 points per thread, strided

#define REPEAT32(M) \
  M(0) M(1) M(2) M(3) M(4) M(5) M(6) M(7) \
  M(8) M(9) M(10) M(11) M(12) M(13) M(14) M(15) \
  M(16) M(17) M(18) M(19) M(20) M(21) M(22) M(23) \
  M(24) M(25) M(26) M(27) M(28) M(29) M(30) M(31)

#define FPS_DECL(i) float px##i, py##i, pz##i, md##i;

#define FPS_INIT(i) { \
    int idx = (i) * FPS_THREADS + t; \
    float lx = P[idx * 3 + 0]; \
    float ly = P[idx * 3 + 1]; \
    float lz = P[idx * 3 + 2]; \
    float li = 1e10f; \
    __asm__("v_accvgpr_write_b32 %0, %1" : "=a"(px##i) : "v"(lx)); \
    __asm__("v_accvgpr_write_b32 %0, %1" : "=a"(py##i) : "v"(ly)); \
    __asm__("v_accvgpr_write_b32 %0, %1" : "=a"(pz##i) : "v"(lz)); \
    __asm__("v_accvgpr_write_b32 %0, %1" : "=a"(md##i) : "v"(li)); }

#define FPS_STEP(i) { \
    float vx, vy, vz, vmd; \
    __asm__("v_accvgpr_read_b32 %0, %1" : "=v"(vx)  : "a"(px##i), "v"(it)); \
    __asm__("v_accvgpr_read_b32 %0, %1" : "=v"(vy)  : "a"(py##i), "v"(it)); \
    __asm__("v_accvgpr_read_b32 %0, %1" : "=v"(vz)  : "a"(pz##i), "v"(it)); \
    __asm__("v_accvgpr_read_b32 %0, %1" : "=v"(vmd) : "a"(md##i), "v"(it)); \
    float dx = __fsub_rn(vx, qx); \
    float dy = __fsub_rn(vy, qy); \
    float dz = __fsub_rn(vz, qz); \
    float d  = __fadd_rn(__fadd_rn(__fmul_rn(dx, dx), __fmul_rn(dy, dy)), \
                         __fmul_rn(dz, dz)); \
    float m = fminf(vmd, d); \
    __asm__("v_accvgpr_write_b32 %0, %1" : "=a"(md##i) : "v"(m)); \
    bool g = (m > best); \
    best = g ? m : best; \
    bi   = g ? (i) : bi; }

__global__ __launch_bounds__(FPS_THREADS)
__attribute__((amdgpu_waves_per_eu(2, 2)))
void fps_kernel(const float* __restrict__ pts, float* __restrict__ out,
                int* __restrict__ ws_ind, float* __restrict__ ws_query) {
  const int b = blockIdx.x;
  const float* P = pts + (size_t)b * NPTS * 3;
  float* out_ind = out;                   // [B,NPOINT] (indices as float)
  float* out_q   = out + BATCH * NPOINT;  // [B,NPOINT,3]
  const int t = threadIdx.x;

  REPEAT32(FPS_DECL)
  REPEAT32(FPS_INIT)

  // parity double-buffered reduce slots: one barrier per iteration
  __shared__ float s_val[2][FPS_THREADS / 64];
  __shared__ int   s_idx[2][FPS_THREADS / 64];

  if (t == 0) {
    out_ind[b * NPOINT] = 0.0f;
    ws_ind[b * NPOINT]  = 0;
    float ax = P[0], ay = P[1], az = P[2];
    out_q[(size_t)(b * NPOINT) * 3 + 0] = ax;
    out_q[(size_t)(b * NPOINT) * 3 + 1] = ay;
    out_q[(size_t)(b * NPOINT) * 3 + 2] = az;
    ws_query[(size_t)(b * NPOINT) * 3 + 0] = ax;
    ws_query[(size_t)(b * NPOINT) * 3 + 1] = ay;
    ws_query[(size_t)(b * NPOINT) * 3 + 2] = az;
  }
  // current selected point (index 0 to start) — broadcast load
  float qx = P[0], qy = P[1], qz = P[2];

  for (int it = 1; it < NPOINT; ++it) {
    const int p = it & 1;
    float best = -1.0f;
    int bi = 0;
    REPEAT32(FPS_STEP)
    int bidx = bi * FPS_THREADS + t;

    // wave argmax reduce, tie -> lower global index
#pragma unroll
    for (int off = 32; off >= 1; off >>= 1) {
      float ov = __shfl_down(best, off);
      int   oi = __shfl_down(bidx, off);
      if (ov > best || (ov == best && oi < bidx)) { best = ov; bidx = oi; }
    }

    if ((t & 63) == 0) { s_val[p][t >> 6] = best; s_idx[p][t >> 6] = bidx; }
    __syncthreads();

    // every thread reduces the 8 wave candidates (redundant, uniform result)
    float bv = s_val[p][0];
    int   bx = s_idx[p][0];
#pragma unroll
    for (int w = 1; w < FPS_THREADS / 64; ++w) {
      float v = s_val[p][w];
      int   x = s_idx[p][w];
      if (v > bv || (v == bv && x < bx)) { bv = v; bx = x; }
    }

    // broadcast load of winner coords (same address across lanes, L1-hot)
    qx = P[bx * 3 + 0];
    qy = P[bx * 3 + 1];
    qz = P[bx * 3 + 2];

    if (t == 0) {
      out_ind[b * NPOINT + it] = (float)bx;
      ws_ind[b * NPOINT + it]  = bx;
      size_t o = (size_t)(b * NPOINT + it) * 3;
      out_q[o + 0] = qx; out_q[o + 1] = qy; out_q[o + 2] = qz;
      ws_query[o + 0] = qx; ws_query[o + 1] = qy; ws_query[o + 2] = qz;
    }
  }
}

// ---------------------------------------------------------------------------
// KNN: one wave per query. Replicates the numpy reference rounding exactly
// (VALIDATED r5-r10, absmax 0.0 — do not change FP semantics):
//   qq,pp : ((x*x + y*y) + z*z), plain rn per op   (contract(off))
//   dot   : fma(z,z', fma(y,y', rn(x*x')))         (BLAS sgemm chain)
//   d     : (qq + pp) - 2*dot, plain rn; max(d, 0)
// Top-(K+1) via u64 key (dist_bits<<32)|idx == stable ascending order;
// per-lane sorted insert, then 21-round wave-min merge; rank 0 dropped.
// ---------------------------------------------------------------------------
#define KNN_WAVES 4

__global__ __launch_bounds__(256)
void knn_kernel(const float* __restrict__ cand_base,   // [B, ncand, 3]
                const float* __restrict__ query_base,  // [B, NPOINT, 3]
                int ncand,
                float* __restrict__ out_nbr,           // [B, NPOINT, K]
                float* __restrict__ out_d) {           // [B, NPOINT, K, 3]
#pragma clang fp contract(off)
  const int wid_in_blk = threadIdx.x >> 6;
  const int w    = blockIdx.x * KNN_WAVES + wid_in_blk;
  const int lane = threadIdx.x & 63;
  const int b    = w / NPOINT;
  const int qi   = w % NPOINT;

  const float* C = cand_base + (size_t)b * ncand * 3;
  const float* Q = query_base + ((size_t)b * NPOINT + qi) * 3;
  const float qx = Q[0], qy = Q[1], qz = Q[2];
  const float qq = (qx * qx + qy * qy) + qz * qz;

  unsigned long long best[KSEL];
#pragma unroll
  for (int j = 0; j < KSEL; ++j) best[j] = 0xFFFFFFFFFFFFFFFFull;

  for (int j = lane; j < ncand; j += 64) {
    float px = C[j * 3 + 0], py = C[j * 3 + 1], pz = C[j * 3 + 2];
    float pp  = (px * px + py * py) + pz * pz;
    // BLAS sgemm inner product: FMA accumulate, k ascending, acc starts 0
    float dot = __builtin_fmaf(qz, pz, __builtin_fmaf(qy, py, qx * px));
    float d = (qq + pp) - 2.0f * dot;
    d = fmaxf(d, 0.0f);
    unsigned long long key =
        ((unsigned long long)__float_as_uint(d) << 32) | (unsigned int)j;
    if (key < best[KSEL - 1]) {
      unsigned long long c = key;
#pragma unroll
      for (int s = 0; s < KSEL; ++s) {
        unsigned long long o = best[s];
        bool l = c < o;
        unsigned long long nb = l ? c : o;
        c = l ? o : c;
        best[s] = nb;
      }
    }
  }

  // dump each lane's sorted list to LDS
  __shared__ unsigned long long s_list[KNN_WAVES][64 * KSEL];
  unsigned long long* L = s_list[wid_in_blk];
#pragma unroll
  for (int j = 0; j < KSEL; ++j) L[lane * KSEL + j] = best[j];
  __syncthreads();

  int hp = 0;      // per-lane head pointer into its own sorted list
  int myK = -1, myIdx = 0;
  for (int r = 0; r < KSEL; ++r) {
    unsigned long long v = L[lane * KSEL + hp];
    int src = lane;
#pragma unroll
    for (int off = 32; off >= 1; off >>= 1) {
      unsigned long long ov = __shfl_down(v, off);
      int os = __shfl_down(src, off);
      if (ov < v) { v = ov; src = os; }  // keys unique (idx embedded)
    }
    v   = __shfl(v, 0);
    src = __shfl(src, 0);
    if (lane == src) hp++;
    if (r >= 1 && lane == r - 1) {       // drop r==0 (self)
      myIdx = (int)(unsigned int)(v & 0xFFFFFFFFull);
      myK = r - 1;
    }
  }

  if (myK >= 0) {  // lanes 0..19 write neighbor k = lane
    size_t o = (size_t)(b * NPOINT + qi) * KNN + myK;
    out_nbr[o] = (float)myIdx;
    float sx = C[myIdx * 3 + 0], sy = C[myIdx * 3 + 1], sz = C[myIdx * 3 + 2];
    out_d[o * 3 + 0] = qx - sx;
    out_d[o * 3 + 1] = qy - sy;
    out_d[o * 3 + 2] = qz - sz;
  }
}

// ---------------------------------------------------------------------------
extern "C" void kernel_launch(void* const* d_in, const int* in_sizes, int n_in,
                              void* d_out, int out_size, void* d_ws,
                              size_t ws_size, hipStream_t stream) {
  (void)in_sizes; (void)n_in; (void)out_size; (void)ws_size;
  const float* pts = (const float*)d_in[0];
  float* out = (float*)d_out;

  int*   ws_ind   = (int*)d_ws;
  float* ws_query = (float*)((char*)d_ws + (size_t)BATCH * NPOINT * sizeof(int));

  // output layout (floats): [xyz_ind | xyz_query | nbr_mid | d_mid | nbr_out | d_out]
  float* out_nbr_mid = out + (size_t)BATCH * NPOINT * 4;            // 16384
  float* out_d_mid   = out_nbr_mid + (size_t)BATCH * NPOINT * KNN;  // +81920
  float* out_nbr_out = out_d_mid + (size_t)BATCH * NPOINT * KNN * 3;
  float* out_d_out   = out_nbr_out + (size_t)BATCH * NPOINT * KNN;

  hipLaunchKernelGGL(fps_kernel, dim3(BATCH), dim3(FPS_THREADS), 0, stream,
                     pts, out, ws_ind, ws_query);

  hipLaunchKernelGGL(knn_kernel, dim3(BATCH * NPOINT / KNN_WAVES), dim3(256),
                     0, stream, pts, ws_query, NPTS, out_nbr_mid, out_d_mid);

  hipLaunchKernelGGL(knn_kernel, dim3(BATCH * NPOINT / KNN_WAVES), dim3(256),
                     0, stream, ws_query, ws_query, NPOINT, out_nbr_out,
                     out_d_out);
}

// Round 12
// 3037.824 us; speedup vs baseline: 1.0662x; 1.0662x over previous
//
#include <hip/hip_runtime.h>
#include <stdint.h>

#define BATCH   4
#define NPTS    16384
#define NPOINT  1024
#define KNN     20
#define KSEL    21   // K+1, includes self

typedef unsigned long long u64;

// ---------------------------------------------------------------------------
// FPS: MULTI-CU. r5-r11 showed the 1-CU-per-batch design is pinned at
// ~5500 cyc/iter across 6 data-path variants (scratch/LDS/AGPR/...) — the
// serial compute->reduce->broadcast chain on 4/256 CUs is the constraint.
// New design: 16 blocks x 256 thr per batch (PPT=4 -> no spill pressure).
// Per iteration: block partial argmax -> packed u64 publish to a
// per-iteration slot row in ws (device-scope release) -> ALL blocks
// spin-read the 16 slots (acquire) and reduce symmetrically (no second
// round-trip). Published = bit63==0 (md>=0) AND 10-bit it-tag matches:
// 0xAA poison (bit63=1) and zeroed ws (tag 0) both read "unpublished";
// deterministic values make stale replays idempotent. Partial-argmax
// decomposition is exact under (max val, min idx) tie-break, and FPS_STEP's
// expression text is unchanged from the validated r5 binary -> identical
// selections.
// ---------------------------------------------------------------------------
#define FPS_SUBS 16                 // blocks per batch
#define FPS_TPB  256                // threads per block
#define FPS_GT   (FPS_SUBS * FPS_TPB)  // 4096 threads per batch
#define FPS_PPT  (NPTS / FPS_GT)    // 4 points per thread

#define REPEAT4(M) M(0) M(1) M(2) M(3)

#define FPS_DECL(i) float px##i, py##i, pz##i, md##i;

#define FPS_INIT(i) { \
    int idx = (i) * FPS_GT + g; \
    px##i = P[idx * 3 + 0]; \
    py##i = P[idx * 3 + 1]; \
    pz##i = P[idx * 3 + 2]; \
    md##i = 1e10f; }

#define FPS_STEP(i) { \
    float dx = __fsub_rn(px##i, qx); \
    float dy = __fsub_rn(py##i, qy); \
    float dz = __fsub_rn(pz##i, qz); \
    float d  = __fadd_rn(__fadd_rn(__fmul_rn(dx, dx), __fmul_rn(dy, dy)), \
                         __fmul_rn(dz, dz)); \
    float m = fminf(md##i, d); \
    md##i = m; \
    bool g2 = (m > best); \
    best = g2 ? m : best; \
    bi   = g2 ? (i) : bi; }

__global__ __launch_bounds__(FPS_TPB)
void fps_kernel(const float* __restrict__ pts, float* __restrict__ out,
                int* __restrict__ ws_ind, float* __restrict__ ws_query,
                u64* __restrict__ slots) {
  const int blk = blockIdx.x;
  const int b   = blk >> 4;          // batch
  const int sub = blk & 15;          // sub-block within batch
  const int t   = threadIdx.x;
  const int g   = sub * FPS_TPB + t; // 0..4095 within batch
  const float* P = pts + (size_t)b * NPTS * 3;
  float* out_ind = out;                   // [B,NPOINT] (indices as float)
  float* out_q   = out + BATCH * NPOINT;  // [B,NPOINT,3]

  REPEAT4(FPS_DECL)
  REPEAT4(FPS_INIT)

  __shared__ float s_val[FPS_TPB / 64];
  __shared__ int   s_idx[FPS_TPB / 64];
  __shared__ int   s_widx;

  if (sub == 0 && t == 0) {
    out_ind[b * NPOINT] = 0.0f;
    ws_ind[b * NPOINT]  = 0;
    float ax = P[0], ay = P[1], az = P[2];
    size_t o0 = (size_t)(b * NPOINT) * 3;
    out_q[o0 + 0] = ax; out_q[o0 + 1] = ay; out_q[o0 + 2] = az;
    ws_query[o0 + 0] = ax; ws_query[o0 + 1] = ay; ws_query[o0 + 2] = az;
  }
  float qx = P[0], qy = P[1], qz = P[2];

  for (int it = 1; it < NPOINT; ++it) {
    float best = -1.0f;
    int bi = 0;
    REPEAT4(FPS_STEP)
    int bidx = bi * FPS_GT + g;      // global point index within batch

    // wave argmax reduce, tie -> lower global index
#pragma unroll
    for (int off = 32; off >= 1; off >>= 1) {
      float ov = __shfl_down(best, off);
      int   oi = __shfl_down(bidx, off);
      if (ov > best || (ov == best && oi < bidx)) { best = ov; bidx = oi; }
    }
    if ((t & 63) == 0) { s_val[t >> 6] = best; s_idx[t >> 6] = bidx; }
    __syncthreads();

    if (t < 64) {
      // cross-wave reduce (uniform, 4 entries)
      float bv = s_val[0];
      int   bx = s_idx[0];
#pragma unroll
      for (int w = 1; w < FPS_TPB / 64; ++w) {
        float v = s_val[w];
        int   x = s_idx[w];
        if (v > bv || (v == bv && x < bx)) { bv = v; bx = x; }
      }
      u64* row = slots + (size_t)it * (BATCH * FPS_SUBS) + b * FPS_SUBS;
      if (t == 0) {
        // publish: [63:32]=md bits (sign=0), [29:20]=it tag, [13:0]=idx
        u64 pv = ((u64)__float_as_uint(bv) << 32) |
                 (unsigned)(bx | (it << 20));
        __hip_atomic_store(&row[sub], pv, __ATOMIC_RELEASE,
                           __HIP_MEMORY_SCOPE_AGENT);
      }
      // spin until all 16 partials for THIS iteration are visible
      int j = t & 15;
      u64 v;
      do {
        v = __hip_atomic_load(&row[j], __ATOMIC_ACQUIRE,
                              __HIP_MEMORY_SCOPE_AGENT);
      } while ((v >> 63) != 0 ||
               (((unsigned)(v >> 20)) & 0x3FFu) != (unsigned)it);
      float fv = __uint_as_float((unsigned)(v >> 32));
      int   fi = (int)((unsigned)v & 0xFFFFFu);
      // 16-way argmax across lanes 0..15 (lanes 16+ hold duplicates,
      // never read by lanes <16 in down-shifts)
#pragma unroll
      for (int off = 8; off >= 1; off >>= 1) {
        float ofv = __shfl_down(fv, off);
        int   ofi = __shfl_down(fi, off);
        if (ofv > fv || (ofv == fv && ofi < fi)) { fv = ofv; fi = ofi; }
      }
      if (t == 0) s_widx = fi;
    }
    __syncthreads();
    const int widx = s_widx;

    // winner coords: uniform broadcast load (L1/L2-hot)
    qx = P[widx * 3 + 0];
    qy = P[widx * 3 + 1];
    qz = P[widx * 3 + 2];

    if (sub == 0 && t == 0) {
      out_ind[b * NPOINT + it] = (float)widx;
      ws_ind[b * NPOINT + it]  = widx;
      size_t o = (size_t)(b * NPOINT + it) * 3;
      out_q[o + 0] = qx; out_q[o + 1] = qy; out_q[o + 2] = qz;
      ws_query[o + 0] = qx; ws_query[o + 1] = qy; ws_query[o + 2] = qz;
    }
  }
}

// ---------------------------------------------------------------------------
// KNN: one wave per query. Replicates the numpy reference rounding exactly
// (VALIDATED r5-r11, absmax 0.0 — do not change FP semantics):
//   qq,pp : ((x*x + y*y) + z*z), plain rn per op   (contract(off))
//   dot   : fma(z,z', fma(y,y', rn(x*x')))         (BLAS sgemm chain)
//   d     : (qq + pp) - 2*dot, plain rn; max(d, 0)
// Top-(K+1) via u64 key (dist_bits<<32)|idx == stable ascending order;
// per-lane sorted insert, then 21-round wave-min merge; rank 0 dropped.
// ---------------------------------------------------------------------------
#define KNN_WAVES 4

__global__ __launch_bounds__(256)
void knn_kernel(const float* __restrict__ cand_base,   // [B, ncand, 3]
                const float* __restrict__ query_base,  // [B, NPOINT, 3]
                int ncand,
                float* __restrict__ out_nbr,           // [B, NPOINT, K]
                float* __restrict__ out_d) {           // [B, NPOINT, K, 3]
#pragma clang fp contract(off)
  const int wid_in_blk = threadIdx.x >> 6;
  const int w    = blockIdx.x * KNN_WAVES + wid_in_blk;
  const int lane = threadIdx.x & 63;
  const int b    = w / NPOINT;
  const int qi   = w % NPOINT;

  const float* C = cand_base + (size_t)b * ncand * 3;
  const float* Q = query_base + ((size_t)b * NPOINT + qi) * 3;
  const float qx = Q[0], qy = Q[1], qz = Q[2];
  const float qq = (qx * qx + qy * qy) + qz * qz;

  unsigned long long best[KSEL];
#pragma unroll
  for (int j = 0; j < KSEL; ++j) best[j] = 0xFFFFFFFFFFFFFFFFull;

  for (int j = lane; j < ncand; j += 64) {
    float px = C[j * 3 + 0], py = C[j * 3 + 1], pz = C[j * 3 + 2];
    float pp  = (px * px + py * py) + pz * pz;
    // BLAS sgemm inner product: FMA accumulate, k ascending, acc starts 0
    float dot = __builtin_fmaf(qz, pz, __builtin_fmaf(qy, py, qx * px));
    float d = (qq + pp) - 2.0f * dot;
    d = fmaxf(d, 0.0f);
    unsigned long long key =
        ((unsigned long long)__float_as_uint(d) << 32) | (unsigned int)j;
    if (key < best[KSEL - 1]) {
      unsigned long long c = key;
#pragma unroll
      for (int s = 0; s < KSEL; ++s) {
        unsigned long long o = best[s];
        bool l = c < o;
        unsigned long long nb = l ? c : o;
        c = l ? o : c;
        best[s] = nb;
      }
    }
  }

  // dump each lane's sorted list to LDS
  __shared__ unsigned long long s_list[KNN_WAVES][64 * KSEL];
  unsigned long long* L = s_list[wid_in_blk];
#pragma unroll
  for (int j = 0; j < KSEL; ++j) L[lane * KSEL + j] = best[j];
  __syncthreads();

  int hp = 0;      // per-lane head pointer into its own sorted list
  int myK = -1, myIdx = 0;
  for (int r = 0; r < KSEL; ++r) {
    unsigned long long v = L[lane * KSEL + hp];
    int src = lane;
#pragma unroll
    for (int off = 32; off >= 1; off >>= 1) {
      unsigned long long ov = __shfl_down(v, off);
      int os = __shfl_down(src, off);
      if (ov < v) { v = ov; src = os; }  // keys unique (idx embedded)
    }
    v   = __shfl(v, 0);
    src = __shfl(src, 0);
    if (lane == src) hp++;
    if (r >= 1 && lane == r - 1) {       // drop r==0 (self)
      myIdx = (int)(unsigned int)(v & 0xFFFFFFFFull);
      myK = r - 1;
    }
  }

  if (myK >= 0) {  // lanes 0..19 write neighbor k = lane
    size_t o = (size_t)(b * NPOINT + qi) * KNN + myK;
    out_nbr[o] = (float)myIdx;
    float sx = C[myIdx * 3 + 0], sy = C[myIdx * 3 + 1], sz = C[myIdx * 3 + 2];
    out_d[o * 3 + 0] = qx - sx;
    out_d[o * 3 + 1] = qy - sy;
    out_d[o * 3 + 2] = qz - sz;
  }
}

// ---------------------------------------------------------------------------
extern "C" void kernel_launch(void* const* d_in, const int* in_sizes, int n_in,
                              void* d_out, int out_size, void* d_ws,
                              size_t ws_size, hipStream_t stream) {
  (void)in_sizes; (void)n_in; (void)out_size; (void)ws_size;
  const float* pts = (const float*)d_in[0];
  float* out = (float*)d_out;

  // ws layout: ind (16KB) | query (48KB) | slots (1024 x 64 x 8B = 512KB)
  int*   ws_ind   = (int*)d_ws;
  float* ws_query = (float*)((char*)d_ws + (size_t)BATCH * NPOINT * sizeof(int));
  u64*   slots    = (u64*)((char*)d_ws + 64 * 1024);

  // output layout (floats): [xyz_ind | xyz_query | nbr_mid | d_mid | nbr_out | d_out]
  float* out_nbr_mid = out + (size_t)BATCH * NPOINT * 4;            // 16384
  float* out_d_mid   = out_nbr_mid + (size_t)BATCH * NPOINT * KNN;  // +81920
  float* out_nbr_out = out_d_mid + (size_t)BATCH * NPOINT * KNN * 3;
  float* out_d_out   = out_nbr_out + (size_t)BATCH * NPOINT * KNN;

  hipLaunchKernelGGL(fps_kernel, dim3(BATCH * FPS_SUBS), dim3(FPS_TPB), 0,
                     stream, pts, out, ws_ind, ws_query, slots);

  hipLaunchKernelGGL(knn_kernel, dim3(BATCH * NPOINT / KNN_WAVES), dim3(256),
                     0, stream, pts, ws_query, NPTS, out_nbr_mid, out_d_mid);

  hipLaunchKernelGGL(knn_kernel, dim3(BATCH * NPOINT / KNN_WAVES), dim3(256),
                     0, stream, ws_query, ws_query, NPOINT, out_nbr_out,
                     out_d_out);
}

// Round 13
// 2785.656 us; speedup vs baseline: 1.1627x; 1.0905x over previous
//
#include <hip/hip_runtime.h>
#include <stdint.h>

#define BATCH   4
#define NPTS    16384
#define NPOINT  1024
#define KNN     20
#define KSEL    21   // K+1, includes self

typedef unsigned long long u64;

// ---------------------------------------------------------------------------
// FPS: MULTI-CU, 16 blocks x 256 thr per batch (PPT=4, VGPR=20, no spill).
// r12 lesson: ACQUIRE polls emit buffer_inv -> per-XCD L2 wiped EVERY poll
// (FETCH 411KB -> 5.4MB, ~6000 cyc/iter at HBM latency). All communicated
// data is inside the single u64 slot word, so RELAXED is correct for both
// publish and poll: cross-XCD visibility via LLC coherence point, no cache
// maintenance. Published = bit63==0 AND 10-bit it-tag matches: 0xAA poison
// (bit63=1) and zeroed ws (tag 0) read "unpublished"; deterministic values
// make stale replays idempotent. Partial-argmax decomposition is exact under
// (max val, min idx) tie-break; FPS_STEP expression text unchanged from the
// validated r5 binary -> identical selections.
// ---------------------------------------------------------------------------
#define FPS_SUBS 16                 // blocks per batch
#define FPS_TPB  256                // threads per block
#define FPS_GT   (FPS_SUBS * FPS_TPB)  // 4096 threads per batch
#define FPS_PPT  (NPTS / FPS_GT)    // 4 points per thread

#define REPEAT4(M) M(0) M(1) M(2) M(3)

#define FPS_DECL(i) float px##i, py##i, pz##i, md##i;

#define FPS_INIT(i) { \
    int idx = (i) * FPS_GT + g; \
    px##i = P[idx * 3 + 0]; \
    py##i = P[idx * 3 + 1]; \
    pz##i = P[idx * 3 + 2]; \
    md##i = 1e10f; }

#define FPS_STEP(i) { \
    float dx = __fsub_rn(px##i, qx); \
    float dy = __fsub_rn(py##i, qy); \
    float dz = __fsub_rn(pz##i, qz); \
    float d  = __fadd_rn(__fadd_rn(__fmul_rn(dx, dx), __fmul_rn(dy, dy)), \
                         __fmul_rn(dz, dz)); \
    float m = fminf(md##i, d); \
    md##i = m; \
    bool g2 = (m > best); \
    best = g2 ? m : best; \
    bi   = g2 ? (i) : bi; }

__global__ __launch_bounds__(FPS_TPB)
void fps_kernel(const float* __restrict__ pts, float* __restrict__ out,
                int* __restrict__ ws_ind, float* __restrict__ ws_query,
                u64* __restrict__ slots) {
  const int blk = blockIdx.x;
  const int b   = blk >> 4;          // batch
  const int sub = blk & 15;          // sub-block within batch
  const int t   = threadIdx.x;
  const int g   = sub * FPS_TPB + t; // 0..4095 within batch
  const float* P = pts + (size_t)b * NPTS * 3;
  float* out_ind = out;                   // [B,NPOINT] (indices as float)
  float* out_q   = out + BATCH * NPOINT;  // [B,NPOINT,3]

  REPEAT4(FPS_DECL)
  REPEAT4(FPS_INIT)

  __shared__ float s_val[FPS_TPB / 64];
  __shared__ int   s_idx[FPS_TPB / 64];
  __shared__ int   s_widx;

  if (sub == 0 && t == 0) {
    out_ind[b * NPOINT] = 0.0f;
    ws_ind[b * NPOINT]  = 0;
    float ax = P[0], ay = P[1], az = P[2];
    size_t o0 = (size_t)(b * NPOINT) * 3;
    out_q[o0 + 0] = ax; out_q[o0 + 1] = ay; out_q[o0 + 2] = az;
    ws_query[o0 + 0] = ax; ws_query[o0 + 1] = ay; ws_query[o0 + 2] = az;
  }
  float qx = P[0], qy = P[1], qz = P[2];

  for (int it = 1; it < NPOINT; ++it) {
    float best = -1.0f;
    int bi = 0;
    REPEAT4(FPS_STEP)
    int bidx = bi * FPS_GT + g;      // global point index within batch

    // wave argmax reduce, tie -> lower global index
#pragma unroll
    for (int off = 32; off >= 1; off >>= 1) {
      float ov = __shfl_down(best, off);
      int   oi = __shfl_down(bidx, off);
      if (ov > best || (ov == best && oi < bidx)) { best = ov; bidx = oi; }
    }
    if ((t & 63) == 0) { s_val[t >> 6] = best; s_idx[t >> 6] = bidx; }
    __syncthreads();

    if (t < 64) {
      // cross-wave reduce (uniform, 4 entries)
      float bv = s_val[0];
      int   bx = s_idx[0];
#pragma unroll
      for (int w = 1; w < FPS_TPB / 64; ++w) {
        float v = s_val[w];
        int   x = s_idx[w];
        if (v > bv || (v == bv && x < bx)) { bv = v; bx = x; }
      }
      u64* row = slots + (size_t)it * (BATCH * FPS_SUBS) + b * FPS_SUBS;
      if (t == 0) {
        // publish: [63:32]=md bits (sign=0), [29:20]=it tag, [13:0]=idx
        // RELAXED: the u64 word IS the entire payload; no cache maintenance
        u64 pv = ((u64)__float_as_uint(bv) << 32) |
                 (unsigned)(bx | (it << 20));
        __hip_atomic_store(&row[sub], pv, __ATOMIC_RELAXED,
                           __HIP_MEMORY_SCOPE_AGENT);
      }
      // spin until all 16 partials for THIS iteration are visible
      int j = t & 15;
      u64 v;
      do {
        v = __hip_atomic_load(&row[j], __ATOMIC_RELAXED,
                              __HIP_MEMORY_SCOPE_AGENT);
      } while ((v >> 63) != 0 ||
               (((unsigned)(v >> 20)) & 0x3FFu) != (unsigned)it);
      float fv = __uint_as_float((unsigned)(v >> 32));
      int   fi = (int)((unsigned)v & 0xFFFFFu);
      // 16-way argmax across lanes 0..15
#pragma unroll
      for (int off = 8; off >= 1; off >>= 1) {
        float ofv = __shfl_down(fv, off);
        int   ofi = __shfl_down(fi, off);
        if (ofv > fv || (ofv == fv && ofi < fi)) { fv = ofv; fi = ofi; }
      }
      if (t == 0) s_widx = fi;
    }
    __syncthreads();
    const int widx = s_widx;

    // winner coords: uniform broadcast load (L2-hot now that inv is gone)
    qx = P[widx * 3 + 0];
    qy = P[widx * 3 + 1];
    qz = P[widx * 3 + 2];

    if (sub == 0 && t == 0) {
      out_ind[b * NPOINT + it] = (float)widx;
      ws_ind[b * NPOINT + it]  = widx;
      size_t o = (size_t)(b * NPOINT + it) * 3;
      out_q[o + 0] = qx; out_q[o + 1] = qy; out_q[o + 2] = qz;
      ws_query[o + 0] = qx; ws_query[o + 1] = qy; ws_query[o + 2] = qz;
    }
  }
}

// ---------------------------------------------------------------------------
// KNN: one wave per query. Replicates the numpy reference rounding exactly
// (VALIDATED r5-r12, absmax 0.0 — do not change FP semantics):
//   qq,pp : ((x*x + y*y) + z*z), plain rn per op   (contract(off))
//   dot   : fma(z,z', fma(y,y', rn(x*x')))         (BLAS sgemm chain)
//   d     : (qq + pp) - 2*dot, plain rn; max(d, 0)
// Top-(K+1) via u64 key (dist_bits<<32)|idx == stable ascending order;
// per-lane sorted insert, then 21-round wave-min merge; rank 0 dropped.
// ---------------------------------------------------------------------------
#define KNN_WAVES 4

__global__ __launch_bounds__(256)
void knn_kernel(const float* __restrict__ cand_base,   // [B, ncand, 3]
                const float* __restrict__ query_base,  // [B, NPOINT, 3]
                int ncand,
                float* __restrict__ out_nbr,           // [B, NPOINT, K]
                float* __restrict__ out_d) {           // [B, NPOINT, K, 3]
#pragma clang fp contract(off)
  const int wid_in_blk = threadIdx.x >> 6;
  const int w    = blockIdx.x * KNN_WAVES + wid_in_blk;
  const int lane = threadIdx.x & 63;
  const int b    = w / NPOINT;
  const int qi   = w % NPOINT;

  const float* C = cand_base + (size_t)b * ncand * 3;
  const float* Q = query_base + ((size_t)b * NPOINT + qi) * 3;
  const float qx = Q[0], qy = Q[1], qz = Q[2];
  const float qq = (qx * qx + qy * qy) + qz * qz;

  unsigned long long best[KSEL];
#pragma unroll
  for (int j = 0; j < KSEL; ++j) best[j] = 0xFFFFFFFFFFFFFFFFull;

  for (int j = lane; j < ncand; j += 64) {
    float px = C[j * 3 + 0], py = C[j * 3 + 1], pz = C[j * 3 + 2];
    float pp  = (px * px + py * py) + pz * pz;
    // BLAS sgemm inner product: FMA accumulate, k ascending, acc starts 0
    float dot = __builtin_fmaf(qz, pz, __builtin_fmaf(qy, py, qx * px));
    float d = (qq + pp) - 2.0f * dot;
    d = fmaxf(d, 0.0f);
    unsigned long long key =
        ((unsigned long long)__float_as_uint(d) << 32) | (unsigned int)j;
    if (key < best[KSEL - 1]) {
      unsigned long long c = key;
#pragma unroll
      for (int s = 0; s < KSEL; ++s) {
        unsigned long long o = best[s];
        bool l = c < o;
        unsigned long long nb = l ? c : o;
        c = l ? o : c;
        best[s] = nb;
      }
    }
  }

  // dump each lane's sorted list to LDS
  __shared__ unsigned long long s_list[KNN_WAVES][64 * KSEL];
  unsigned long long* L = s_list[wid_in_blk];
#pragma unroll
  for (int j = 0; j < KSEL; ++j) L[lane * KSEL + j] = best[j];
  __syncthreads();

  int hp = 0;      // per-lane head pointer into its own sorted list
  int myK = -1, myIdx = 0;
  for (int r = 0; r < KSEL; ++r) {
    unsigned long long v = L[lane * KSEL + hp];
    int src = lane;
#pragma unroll
    for (int off = 32; off >= 1; off >>= 1) {
      unsigned long long ov = __shfl_down(v, off);
      int os = __shfl_down(src, off);
      if (ov < v) { v = ov; src = os; }  // keys unique (idx embedded)
    }
    v   = __shfl(v, 0);
    src = __shfl(src, 0);
    if (lane == src) hp++;
    if (r >= 1 && lane == r - 1) {       // drop r==0 (self)
      myIdx = (int)(unsigned int)(v & 0xFFFFFFFFull);
      myK = r - 1;
    }
  }

  if (myK >= 0) {  // lanes 0..19 write neighbor k = lane
    size_t o = (size_t)(b * NPOINT + qi) * KNN + myK;
    out_nbr[o] = (float)myIdx;
    float sx = C[myIdx * 3 + 0], sy = C[myIdx * 3 + 1], sz = C[myIdx * 3 + 2];
    out_d[o * 3 + 0] = qx - sx;
    out_d[o * 3 + 1] = qy - sy;
    out_d[o * 3 + 2] = qz - sz;
  }
}

// ---------------------------------------------------------------------------
extern "C" void kernel_launch(void* const* d_in, const int* in_sizes, int n_in,
                              void* d_out, int out_size, void* d_ws,
                              size_t ws_size, hipStream_t stream) {
  (void)in_sizes; (void)n_in; (void)out_size; (void)ws_size;
  const float* pts = (const float*)d_in[0];
  float* out = (float*)d_out;

  // ws layout: ind (16KB) | query (48KB) | slots (1024 x 64 x 8B = 512KB)
  int*   ws_ind   = (int*)d_ws;
  float* ws_query = (float*)((char*)d_ws + (size_t)BATCH * NPOINT * sizeof(int));
  u64*   slots    = (u64*)((char*)d_ws + 64 * 1024);

  // output layout (floats): [xyz_ind | xyz_query | nbr_mid | d_mid | nbr_out | d_out]
  float* out_nbr_mid = out + (size_t)BATCH * NPOINT * 4;            // 16384
  float* out_d_mid   = out_nbr_mid + (size_t)BATCH * NPOINT * KNN;  // +81920
  float* out_nbr_out = out_d_mid + (size_t)BATCH * NPOINT * KNN * 3;
  float* out_d_out   = out_nbr_out + (size_t)BATCH * NPOINT * KNN;

  hipLaunchKernelGGL(fps_kernel, dim3(BATCH * FPS_SUBS), dim3(FPS_TPB), 0,
                     stream, pts, out, ws_ind, ws_query, slots);

  hipLaunchKernelGGL(knn_kernel, dim3(BATCH * NPOINT / KNN_WAVES), dim3(256),
                     0, stream, pts, ws_query, NPTS, out_nbr_mid, out_d_mid);

  hipLaunchKernelGGL(knn_kernel, dim3(BATCH * NPOINT / KNN_WAVES), dim3(256),
                     0, stream, ws_query, ws_query, NPOINT, out_nbr_out,
                     out_d_out);
}

// Round 14
// 2737.136 us; speedup vs baseline: 1.1833x; 1.0177x over previous
//
#include <hip/hip_runtime.h>
#include <stdint.h>

#define BATCH   4
#define NPTS    16384
#define NPOINT  1024
#define KNN     20
#define KSEL    21   // K+1, includes self

typedef unsigned long long u64;

// ---------------------------------------------------------------------------
// FUSED kernel: blocks 0..63 = FPS (exact r13 protocol, validated absmax 0.0);
// blocks 64..1087 = knn_mid consumers, 4 queries/block (1 wave each), which
// poll the SAME per-iteration slot rows, reduce the 16 partials with the
// identical (max val, min idx) tie-break (-> bit-identical widx), read q from
// P[widx] (bit-identical to ws_query), and run the validated scan.
// No LDS / no barriers in the knn role: all 1088 blocks (4352 waves, <=~80
// VGPR) are co-resident -> no deadlock regardless of dispatch order.
// Rationale: 8 fps variants all pinned at ~2.2-2.4us/iter (likely clock-
// throttled at 1-3% chip utilization); fusing hides knn_mid's ~400us AND
// raises utilization so clocks can ramp.
// ---------------------------------------------------------------------------
#define FPS_SUBS 16                 // fps blocks per batch
#define FPS_TPB  256                // threads per block (both roles)
#define FPS_BLOCKS (BATCH * FPS_SUBS)            // 64
#define FPS_GT   (FPS_SUBS * FPS_TPB)            // 4096 threads per batch
#define FPS_PPT  (NPTS / FPS_GT)                 // 4 points per thread
#define KNN_BLOCKS (BATCH * NPOINT / 4)          // 1024 (4 waves/block)

#define REPEAT4(M) M(0) M(1) M(2) M(3)

#define FPS_DECL(i) float px##i, py##i, pz##i, md##i;

#define FPS_INIT(i) { \
    int idx = (i) * FPS_GT + g; \
    px##i = P[idx * 3 + 0]; \
    py##i = P[idx * 3 + 1]; \
    pz##i = P[idx * 3 + 2]; \
    md##i = 1e10f; }

#define FPS_STEP(i) { \
    float dx = __fsub_rn(px##i, qx); \
    float dy = __fsub_rn(py##i, qy); \
    float dz = __fsub_rn(pz##i, qz); \
    float d  = __fadd_rn(__fadd_rn(__fmul_rn(dx, dx), __fmul_rn(dy, dy)), \
                         __fmul_rn(dz, dz)); \
    float m = fminf(md##i, d); \
    md##i = m; \
    bool g2 = (m > best); \
    best = g2 ? m : best; \
    bi   = g2 ? (i) : bi; }

__global__ __launch_bounds__(FPS_TPB)
void fused_kernel(const float* __restrict__ pts, float* __restrict__ out,
                  int* __restrict__ ws_ind, float* __restrict__ ws_query,
                  u64* __restrict__ slots,
                  float* __restrict__ out_nbr_mid,
                  float* __restrict__ out_d_mid) {
  __shared__ float s_val[FPS_TPB / 64];
  __shared__ int   s_idx[FPS_TPB / 64];
  __shared__ int   s_widx;

  if (blockIdx.x < FPS_BLOCKS) {
    // ---------------- FPS role (exact r13 body) ----------------
    const int blk = blockIdx.x;
    const int b   = blk >> 4;
    const int sub = blk & 15;
    const int t   = threadIdx.x;
    const int g   = sub * FPS_TPB + t;
    const float* P = pts + (size_t)b * NPTS * 3;
    float* out_ind = out;
    float* out_q   = out + BATCH * NPOINT;

    REPEAT4(FPS_DECL)
    REPEAT4(FPS_INIT)

    if (sub == 0 && t == 0) {
      out_ind[b * NPOINT] = 0.0f;
      ws_ind[b * NPOINT]  = 0;
      float ax = P[0], ay = P[1], az = P[2];
      size_t o0 = (size_t)(b * NPOINT) * 3;
      out_q[o0 + 0] = ax; out_q[o0 + 1] = ay; out_q[o0 + 2] = az;
      ws_query[o0 + 0] = ax; ws_query[o0 + 1] = ay; ws_query[o0 + 2] = az;
    }
    float qx = P[0], qy = P[1], qz = P[2];

    for (int it = 1; it < NPOINT; ++it) {
      float best = -1.0f;
      int bi = 0;
      REPEAT4(FPS_STEP)
      int bidx = bi * FPS_GT + g;

#pragma unroll
      for (int off = 32; off >= 1; off >>= 1) {
        float ov = __shfl_down(best, off);
        int   oi = __shfl_down(bidx, off);
        if (ov > best || (ov == best && oi < bidx)) { best = ov; bidx = oi; }
      }
      if ((t & 63) == 0) { s_val[t >> 6] = best; s_idx[t >> 6] = bidx; }
      __syncthreads();

      if (t < 64) {
        float bv = s_val[0];
        int   bx = s_idx[0];
#pragma unroll
        for (int w = 1; w < FPS_TPB / 64; ++w) {
          float v = s_val[w];
          int   x = s_idx[w];
          if (v > bv || (v == bv && x < bx)) { bv = v; bx = x; }
        }
        u64* row = slots + (size_t)it * (BATCH * FPS_SUBS) + b * FPS_SUBS;
        if (t == 0) {
          u64 pv = ((u64)__float_as_uint(bv) << 32) |
                   (unsigned)(bx | (it << 20));
          __hip_atomic_store(&row[sub], pv, __ATOMIC_RELAXED,
                             __HIP_MEMORY_SCOPE_AGENT);
        }
        int j = t & 15;
        u64 v;
        do {
          v = __hip_atomic_load(&row[j], __ATOMIC_RELAXED,
                                __HIP_MEMORY_SCOPE_AGENT);
        } while ((v >> 63) != 0 ||
                 (((unsigned)(v >> 20)) & 0x3FFu) != (unsigned)it);
        float fv = __uint_as_float((unsigned)(v >> 32));
        int   fi = (int)((unsigned)v & 0xFFFFFu);
#pragma unroll
        for (int off = 8; off >= 1; off >>= 1) {
          float ofv = __shfl_down(fv, off);
          int   ofi = __shfl_down(fi, off);
          if (ofv > fv || (ofv == fv && ofi < fi)) { fv = ofv; fi = ofi; }
        }
        if (t == 0) s_widx = fi;
      }
      __syncthreads();
      const int widx = s_widx;

      qx = P[widx * 3 + 0];
      qy = P[widx * 3 + 1];
      qz = P[widx * 3 + 2];

      if (sub == 0 && t == 0) {
        out_ind[b * NPOINT + it] = (float)widx;
        ws_ind[b * NPOINT + it]  = widx;
        size_t o = (size_t)(b * NPOINT + it) * 3;
        out_q[o + 0] = qx; out_q[o + 1] = qy; out_q[o + 2] = qz;
        ws_query[o + 0] = qx; ws_query[o + 1] = qy; ws_query[o + 2] = qz;
      }
    }
  } else {
    // ---------------- knn_mid role: one wave per query ----------------
#pragma clang fp contract(off)
    const int wv   = (blockIdx.x - FPS_BLOCKS) * 4 + (threadIdx.x >> 6);
    const int lane = threadIdx.x & 63;
    const int b    = wv / NPOINT;
    const int qi   = wv % NPOINT;
    const float* C = pts + (size_t)b * NPTS * 3;

    // --- obtain this query's point index (same protocol+tie-break as fps) ---
    int widx = 0;
    if (qi > 0) {
      u64* row = slots + (size_t)qi * (BATCH * FPS_SUBS) + b * FPS_SUBS;
      int j = lane & 15;
      u64 v;
      for (;;) {
        v = __hip_atomic_load(&row[j], __ATOMIC_RELAXED,
                              __HIP_MEMORY_SCOPE_AGENT);
        bool ok = ((v >> 63) == 0) &&
                  ((((unsigned)(v >> 20)) & 0x3FFu) == (unsigned)qi);
        if (__all(ok)) break;
        __builtin_amdgcn_s_sleep(64);
      }
      float fv = __uint_as_float((unsigned)(v >> 32));
      int   fi = (int)((unsigned)v & 0xFFFFFu);
#pragma unroll
      for (int off = 8; off >= 1; off >>= 1) {
        float ofv = __shfl_down(fv, off);
        int   ofi = __shfl_down(fi, off);
        if (ofv > fv || (ofv == fv && ofi < fi)) { fv = ofv; fi = ofi; }
      }
      widx = __shfl(fi, 0);
    }

    // q coords: bit-identical to ws_query (fps writes exactly P[widx])
    const float qx = C[widx * 3 + 0];
    const float qy = C[widx * 3 + 1];
    const float qz = C[widx * 3 + 2];
    const float qq = (qx * qx + qy * qy) + qz * qz;

    u64 best[KSEL];
#pragma unroll
    for (int j = 0; j < KSEL; ++j) best[j] = 0xFFFFFFFFFFFFFFFFull;

    for (int j = lane; j < NPTS; j += 64) {
      float px = C[j * 3 + 0], py = C[j * 3 + 1], pz = C[j * 3 + 2];
      float pp  = (px * px + py * py) + pz * pz;
      float dot = __builtin_fmaf(qz, pz, __builtin_fmaf(qy, py, qx * px));
      float d = (qq + pp) - 2.0f * dot;
      d = fmaxf(d, 0.0f);
      u64 key = ((u64)__float_as_uint(d) << 32) | (unsigned)j;
      if (key < best[KSEL - 1]) {
        u64 c = key;
#pragma unroll
        for (int s = 0; s < KSEL; ++s) {
          u64 o = best[s];
          bool l = c < o;
          u64 nb = l ? c : o;
          c = l ? o : c;
          best[s] = nb;
        }
      }
    }

    // --- LDS-free 64-way merge: repeated wave-min over per-lane heads ---
    int hp = 1;
    u64 head = best[0];
    int myK = -1, myIdx = 0;
#pragma unroll
    for (int r = 0; r < KSEL; ++r) {
      u64 v = head; int src = lane;
#pragma unroll
      for (int off = 32; off >= 1; off >>= 1) {
        u64 ov = __shfl_down(v, off);
        int os = __shfl_down(src, off);
        if (ov < v) { v = ov; src = os; }  // keys unique (idx embedded)
      }
      v   = __shfl(v, 0);
      src = __shfl(src, 0);
      if (r >= 1 && lane == r - 1) {       // drop r==0 (self)
        myIdx = (int)(unsigned)(v & 0xFFFFFFFFull);
        myK = r - 1;
      }
      if (lane == src) {
        u64 h = 0xFFFFFFFFFFFFFFFFull;
#pragma unroll
        for (int s = 1; s < KSEL; ++s) if (hp == s) h = best[s];
        head = h;
        hp++;
      }
    }

    if (myK >= 0) {  // lanes 0..19 write neighbor k = lane
      size_t o = (size_t)(b * NPOINT + qi) * KNN + myK;
      out_nbr_mid[o] = (float)myIdx;
      float sx = C[myIdx * 3 + 0], sy = C[myIdx * 3 + 1],
            sz = C[myIdx * 3 + 2];
      out_d_mid[o * 3 + 0] = qx - sx;
      out_d_mid[o * 3 + 1] = qy - sy;
      out_d_mid[o * 3 + 2] = qz - sz;
    }
  }
}

// ---------------------------------------------------------------------------
// knn_out: unchanged validated kernel (candidates = the 1024 queries).
// ---------------------------------------------------------------------------
#define KNN_WAVES 4

__global__ __launch_bounds__(256)
void knn_kernel(const float* __restrict__ cand_base,
                const float* __restrict__ query_base,
                int ncand,
                float* __restrict__ out_nbr,
                float* __restrict__ out_d) {
#pragma clang fp contract(off)
  const int wid_in_blk = threadIdx.x >> 6;
  const int w    = blockIdx.x * KNN_WAVES + wid_in_blk;
  const int lane = threadIdx.x & 63;
  const int b    = w / NPOINT;
  const int qi   = w % NPOINT;

  const float* C = cand_base + (size_t)b * ncand * 3;
  const float* Q = query_base + ((size_t)b * NPOINT + qi) * 3;
  const float qx = Q[0], qy = Q[1], qz = Q[2];
  const float qq = (qx * qx + qy * qy) + qz * qz;

  u64 best[KSEL];
#pragma unroll
  for (int j = 0; j < KSEL; ++j) best[j] = 0xFFFFFFFFFFFFFFFFull;

  for (int j = lane; j < ncand; j += 64) {
    float px = C[j * 3 + 0], py = C[j * 3 + 1], pz = C[j * 3 + 2];
    float pp  = (px * px + py * py) + pz * pz;
    float dot = __builtin_fmaf(qz, pz, __builtin_fmaf(qy, py, qx * px));
    float d = (qq + pp) - 2.0f * dot;
    d = fmaxf(d, 0.0f);
    u64 key = ((u64)__float_as_uint(d) << 32) | (unsigned)j;
    if (key < best[KSEL - 1]) {
      u64 c = key;
#pragma unroll
      for (int s = 0; s < KSEL; ++s) {
        u64 o = best[s];
        bool l = c < o;
        u64 nb = l ? c : o;
        c = l ? o : c;
        best[s] = nb;
      }
    }
  }

  __shared__ u64 s_list[KNN_WAVES][64 * KSEL];
  u64* L = s_list[wid_in_blk];
#pragma unroll
  for (int j = 0; j < KSEL; ++j) L[lane * KSEL + j] = best[j];
  __syncthreads();

  int hp = 0;
  int myK = -1, myIdx = 0;
  for (int r = 0; r < KSEL; ++r) {
    u64 v = L[lane * KSEL + hp];
    int src = lane;
#pragma unroll
    for (int off = 32; off >= 1; off >>= 1) {
      u64 ov = __shfl_down(v, off);
      int os = __shfl_down(src, off);
      if (ov < v) { v = ov; src = os; }
    }
    v   = __shfl(v, 0);
    src = __shfl(src, 0);
    if (lane == src) hp++;
    if (r >= 1 && lane == r - 1) {
      myIdx = (int)(unsigned)(v & 0xFFFFFFFFull);
      myK = r - 1;
    }
  }

  if (myK >= 0) {
    size_t o = (size_t)(b * NPOINT + qi) * KNN + myK;
    out_nbr[o] = (float)myIdx;
    float sx = C[myIdx * 3 + 0], sy = C[myIdx * 3 + 1], sz = C[myIdx * 3 + 2];
    out_d[o * 3 + 0] = qx - sx;
    out_d[o * 3 + 1] = qy - sy;
    out_d[o * 3 + 2] = qz - sz;
  }
}

// ---------------------------------------------------------------------------
extern "C" void kernel_launch(void* const* d_in, const int* in_sizes, int n_in,
                              void* d_out, int out_size, void* d_ws,
                              size_t ws_size, hipStream_t stream) {
  (void)in_sizes; (void)n_in; (void)out_size; (void)ws_size;
  const float* pts = (const float*)d_in[0];
  float* out = (float*)d_out;

  // ws layout: ind (16KB) | query (48KB) | slots (1024 x 64 x 8B = 512KB)
  int*   ws_ind   = (int*)d_ws;
  float* ws_query = (float*)((char*)d_ws + (size_t)BATCH * NPOINT * sizeof(int));
  u64*   slots    = (u64*)((char*)d_ws + 64 * 1024);

  // output layout (floats): [xyz_ind | xyz_query | nbr_mid | d_mid | nbr_out | d_out]
  float* out_nbr_mid = out + (size_t)BATCH * NPOINT * 4;
  float* out_d_mid   = out_nbr_mid + (size_t)BATCH * NPOINT * KNN;
  float* out_nbr_out = out_d_mid + (size_t)BATCH * NPOINT * KNN * 3;
  float* out_d_out   = out_nbr_out + (size_t)BATCH * NPOINT * KNN;

  hipLaunchKernelGGL(fused_kernel, dim3(FPS_BLOCKS + KNN_BLOCKS),
                     dim3(FPS_TPB), 0, stream,
                     pts, out, ws_ind, ws_query, slots,
                     out_nbr_mid, out_d_mid);

  hipLaunchKernelGGL(knn_kernel, dim3(BATCH * NPOINT / KNN_WAVES), dim3(256),
                     0, stream, ws_query, ws_query, NPOINT, out_nbr_out,
                     out_d_out);
}